// Round 1
// baseline (476.212 us; speedup 1.0000x reference)
//
#include <hip/hip_runtime.h>
#include <hip/hip_bf16.h>

#define N_NODES 8192
#define DIM 256
#define NLAB 2048
#define NGRAPH 16
#define NSLICE 16
#define TILE 64
#define PADK 68
#define NEG_BIG (-1e30f)
#define INV_T 10.0f

// ---------------- histogram of conserved nodes per (label, graph) ----------------
__global__ void k_counts(const int* __restrict__ labels, const int* __restrict__ graphs,
                         const int* __restrict__ cats, int* __restrict__ cnt, int* __restrict__ tot) {
    int i = blockIdx.x * 256 + threadIdx.x;
    if (i >= N_NODES) return;
    if (cats[i] < 3) {
        atomicAdd(&cnt[labels[i] * NGRAPH + graphs[i]], 1);
        atomicAdd(&tot[labels[i]], 1);
    }
}

// ---------------- compact participating nodes ----------------
__global__ void k_compact(const int* __restrict__ labels, const int* __restrict__ graphs,
                          const int* __restrict__ cats, const int* __restrict__ cnt,
                          const int* __restrict__ tot, int* P_count, int* n_pos,
                          int* __restrict__ idx_c, int* __restrict__ lab_c,
                          int* __restrict__ grf_c, int* __restrict__ rc_c) {
    int i = blockIdx.x * 256 + threadIdx.x;
    if (i >= N_NODES) return;
    if (cats[i] < 3) {
        int l = labels[i], g = graphs[i];
        int rc = tot[l] - cnt[l * NGRAPH + g];  // # positive partners of i
        if (rc > 0) {
            int p = atomicAdd(P_count, 1);
            idx_c[p] = i; lab_c[p] = l; grf_c[p] = g; rc_c[p] = rc;
            atomicAdd(n_pos, rc);
        }
    }
}

// ---------------- gather + L2-normalize participating rows (1 wave / row) ----------------
__global__ void k_gather(const float* __restrict__ emb, const int* __restrict__ P_count,
                         const int* __restrict__ idx_c, float* __restrict__ Ep) {
    int w = threadIdx.x >> 6, lane = threadIdx.x & 63;
    int p = blockIdx.x * 4 + w;
    if (p >= *P_count) return;
    int row = idx_c[p];
    float4 v = *(const float4*)&emb[(size_t)row * DIM + lane * 4];
    float ss = v.x * v.x + v.y * v.y + v.z * v.z + v.w * v.w;
    #pragma unroll
    for (int off = 32; off; off >>= 1) ss += __shfl_xor(ss, off, 64);
    float inv = 1.0f / fmaxf(sqrtf(ss), 1e-12f);
    float4 o; o.x = v.x * inv; o.y = v.y * inv; o.z = v.z * inv; o.w = v.w * inv;
    *(float4*)&Ep[(size_t)p * DIM + lane * 4] = o;
}

// ---------------- main: S = Ep Ep^T tile-by-tile with online logsumexp ----------------
__global__ __launch_bounds__(256) void k_main(
    const float* __restrict__ Ep, const int* __restrict__ P_count,
    const int* __restrict__ lab_c, const int* __restrict__ grf_c,
    float* __restrict__ m_part, float* __restrict__ s_part, float* __restrict__ pos_part) {
    __shared__ float As[TILE * PADK];
    __shared__ float Bs[TILE * PADK];
    int P = *P_count;
    int rt = blockIdx.x;
    if (rt * TILE >= P) return;
    int slice = blockIdx.y;
    int ntiles = (P + TILE - 1) / TILE;
    int cpt = (ntiles + NSLICE - 1) / NSLICE;
    int t0 = slice * cpt;
    int t1 = min(ntiles, t0 + cpt);

    int tx = threadIdx.x & 15, ty = threadIdx.x >> 4;
    int rowbase = rt * TILE + ty * 4;

    int lr[4], gr[4]; bool rowv[4];
    #pragma unroll
    for (int r = 0; r < 4; r++) {
        int p = rowbase + r;
        rowv[r] = p < P;
        lr[r] = rowv[r] ? lab_c[p] : -1;
        gr[r] = rowv[r] ? grf_c[p] : -2;
    }
    float m[4] = {NEG_BIG, NEG_BIG, NEG_BIG, NEG_BIG};
    float s[4] = {0.f, 0.f, 0.f, 0.f};
    float pos[4] = {0.f, 0.f, 0.f, 0.f};

    for (int ct = t0; ct < t1; ++ct) {
        int colbase = ct * TILE;
        float acc[4][4] = {};
        for (int kc = 0; kc < 4; ++kc) {
            __syncthreads();
            #pragma unroll
            for (int it = 0; it < 4; ++it) {
                int idx = threadIdx.x + it * 256;
                int r = idx >> 4, c4 = (idx & 15) * 4;
                int gra = rt * TILE + r;
                float4 va = make_float4(0.f, 0.f, 0.f, 0.f);
                if (gra < P) va = *(const float4*)&Ep[(size_t)gra * DIM + kc * 64 + c4];
                *(float4*)&As[r * PADK + c4] = va;
                int grb = colbase + r;
                float4 vb = make_float4(0.f, 0.f, 0.f, 0.f);
                if (grb < P) vb = *(const float4*)&Ep[(size_t)grb * DIM + kc * 64 + c4];
                *(float4*)&Bs[r * PADK + c4] = vb;
            }
            __syncthreads();
            #pragma unroll
            for (int k4 = 0; k4 < 16; ++k4) {
                float4 a4[4], b4[4];
                #pragma unroll
                for (int j = 0; j < 4; j++) a4[j] = *(const float4*)&As[(ty * 4 + j) * PADK + k4 * 4];
                #pragma unroll
                for (int j = 0; j < 4; j++) b4[j] = *(const float4*)&Bs[(tx * 4 + j) * PADK + k4 * 4];
                #pragma unroll
                for (int r = 0; r < 4; r++)
                    #pragma unroll
                    for (int c = 0; c < 4; c++)
                        acc[r][c] += a4[r].x * b4[c].x + a4[r].y * b4[c].y +
                                     a4[r].z * b4[c].z + a4[r].w * b4[c].w;
            }
        }
        // masking + online logsumexp update
        #pragma unroll
        for (int c = 0; c < 4; c++) {
            int q = colbase + tx * 4 + c;
            if (q >= P) continue;
            int lq = lab_c[q], gq = grf_c[q];
            #pragma unroll
            for (int r = 0; r < 4; r++) {
                if (!rowv[r] || gq == gr[r]) continue;   // valid <=> different graph (diag excluded)
                float sv = acc[r][c];
                float l = sv * INV_T;
                if (l > m[r]) { s[r] = s[r] * __expf(m[r] - l) + 1.0f; m[r] = l; }
                else          { s[r] += __expf(l - m[r]); }
                if (lq == lr[r]) pos[r] += sv;           // positive pair
            }
        }
    }
    // reduce (m,s,pos) across the 16 lanes (tx) sharing each row
    #pragma unroll
    for (int off = 1; off < 16; off <<= 1) {
        #pragma unroll
        for (int r = 0; r < 4; r++) {
            float m2 = __shfl_xor(m[r], off, 64);
            float s2 = __shfl_xor(s[r], off, 64);
            float p2 = __shfl_xor(pos[r], off, 64);
            float M = fmaxf(m[r], m2);
            float sn = 0.f;
            if (s[r] > 0.f) sn += s[r] * __expf(m[r] - M);
            if (s2   > 0.f) sn += s2  * __expf(m2 - M);
            m[r] = M; s[r] = sn; pos[r] += p2;
        }
    }
    if (tx == 0) {
        #pragma unroll
        for (int r = 0; r < 4; r++) {
            int p = rowbase + r;
            if (p < P) {
                m_part[slice * N_NODES + p] = m[r];
                s_part[slice * N_NODES + p] = s[r];
                pos_part[slice * N_NODES + p] = pos[r];
            }
        }
    }
}

// ---------------- final reduce ----------------
__global__ __launch_bounds__(256) void k_reduce(
    const int* __restrict__ P_count, const int* __restrict__ n_pos_p,
    const int* __restrict__ rc_c, const float* __restrict__ m_part,
    const float* __restrict__ s_part, const float* __restrict__ pos_part,
    float* __restrict__ out) {
    __shared__ float red[256];
    __shared__ float red2[256];
    int P = *P_count;
    float nce_local = 0.f, pos_local = 0.f;
    for (int p = threadIdx.x; p < P; p += 256) {
        float M = NEG_BIG;
        for (int sl = 0; sl < NSLICE; sl++) M = fmaxf(M, m_part[sl * N_NODES + p]);
        float S = 0.f, ps = 0.f;
        for (int sl = 0; sl < NSLICE; sl++) {
            float sv = s_part[sl * N_NODES + p];
            if (sv > 0.f) S += sv * __expf(m_part[sl * N_NODES + p] - M);
            ps += pos_part[sl * N_NODES + p];
        }
        float lse = M + logf(S);
        nce_local += (float)rc_c[p] * lse;
        pos_local += ps;
    }
    red[threadIdx.x] = nce_local;
    red2[threadIdx.x] = pos_local;
    __syncthreads();
    for (int w = 128; w; w >>= 1) {
        if (threadIdx.x < (unsigned)w) {
            red[threadIdx.x] += red[threadIdx.x + w];
            red2[threadIdx.x] += red2[threadIdx.x + w];
        }
        __syncthreads();
    }
    if (threadIdx.x == 0) {
        int npos = *n_pos_p;
        float result = 0.f;
        if (npos > 0) {
            float possum = red2[0];
            float n_pairs = (float)(npos / 2);
            float pos_loss = (n_pairs - 0.5f * possum) / n_pairs;
            float nce = (red[0] - possum * INV_T) / (float)npos;
            result = pos_loss + nce;
        }
        out[0] = result;
    }
}

extern "C" void kernel_launch(void* const* d_in, const int* in_sizes, int n_in,
                              void* d_out, int out_size, void* d_ws, size_t ws_size,
                              hipStream_t stream) {
    const float* emb   = (const float*)d_in[0];
    const int* labels  = (const int*)d_in[1];
    const int* graphs  = (const int*)d_in[2];
    const int* cats    = (const int*)d_in[3];

    char* ws = (char*)d_ws;
    size_t off = 0;
    float* Ep = (float*)(ws + off); off += (size_t)N_NODES * DIM * 4;      // 8 MB
    int* cnt     = (int*)(ws + off); off += NLAB * NGRAPH * 4;             // 128 KB  (zeroed)
    int* tot     = (int*)(ws + off); off += NLAB * 4;                      // 8 KB    (zeroed)
    int* P_count = (int*)(ws + off); off += 4;                             // (zeroed)
    int* n_pos   = (int*)(ws + off); off += 4;                             // (zeroed)
    size_t zero_bytes = (size_t)NLAB * NGRAPH * 4 + NLAB * 4 + 8;          // cnt..n_pos contiguous
    off = (off + 255) & ~(size_t)255;
    int* idx_c = (int*)(ws + off); off += N_NODES * 4;
    int* lab_c = (int*)(ws + off); off += N_NODES * 4;
    int* grf_c = (int*)(ws + off); off += N_NODES * 4;
    int* rc_c  = (int*)(ws + off); off += N_NODES * 4;
    float* m_part   = (float*)(ws + off); off += (size_t)NSLICE * N_NODES * 4;
    float* s_part   = (float*)(ws + off); off += (size_t)NSLICE * N_NODES * 4;
    float* pos_part = (float*)(ws + off); off += (size_t)NSLICE * N_NODES * 4;

    hipMemsetAsync(cnt, 0, zero_bytes, stream);
    k_counts<<<N_NODES / 256, 256, 0, stream>>>(labels, graphs, cats, cnt, tot);
    k_compact<<<N_NODES / 256, 256, 0, stream>>>(labels, graphs, cats, cnt, tot,
                                                 P_count, n_pos, idx_c, lab_c, grf_c, rc_c);
    k_gather<<<N_NODES / 4, 256, 0, stream>>>(emb, P_count, idx_c, Ep);
    dim3 grid(N_NODES / TILE, NSLICE);
    k_main<<<grid, 256, 0, stream>>>(Ep, P_count, lab_c, grf_c, m_part, s_part, pos_part);
    k_reduce<<<1, 256, 0, stream>>>(P_count, n_pos, rc_c, m_part, s_part, pos_part, (float*)d_out);
}

// Round 2
// 114.138 us; speedup vs baseline: 4.1722x; 4.1722x over previous
//
#include <hip/hip_runtime.h>
#include <hip/hip_bf16.h>

#define N_NODES 8192
#define DIM 256
#define NLAB 2048
#define NGRAPH 16
#define NSLICE 16
#define INV_T 10.0f

typedef __attribute__((ext_vector_type(8))) short short8;
typedef __attribute__((ext_vector_type(4))) float f32x4;

__device__ __forceinline__ ushort f2bf(float f) {
    uint u = __float_as_uint(f);
    return (ushort)((u + 0x7FFFu + ((u >> 16) & 1u)) >> 16);  // RNE
}

// ---------------- histogram of conserved nodes per (label, graph) ----------------
__global__ void k_counts(const int* __restrict__ labels, const int* __restrict__ graphs,
                         const int* __restrict__ cats, int* __restrict__ cnt, int* __restrict__ tot) {
    int i = blockIdx.x * 256 + threadIdx.x;
    if (i >= N_NODES) return;
    if (cats[i] < 3) {
        atomicAdd(&cnt[labels[i] * NGRAPH + graphs[i]], 1);
        atomicAdd(&tot[labels[i]], 1);
    }
}

// ---------------- compact participating nodes ----------------
__global__ void k_compact(const int* __restrict__ labels, const int* __restrict__ graphs,
                          const int* __restrict__ cats, const int* __restrict__ cnt,
                          const int* __restrict__ tot, int* P_count, int* n_pos,
                          int* __restrict__ idx_c, int* __restrict__ meta,
                          int* __restrict__ rc_c) {
    int i = blockIdx.x * 256 + threadIdx.x;
    if (i >= N_NODES) return;
    if (cats[i] < 3) {
        int l = labels[i], g = graphs[i];
        int rc = tot[l] - cnt[l * NGRAPH + g];  // # positive partners of i
        if (rc > 0) {
            int p = atomicAdd(P_count, 1);
            idx_c[p] = i;
            meta[p] = (l << 4) | g;   // label in high bits, graph in low nibble
            rc_c[p] = rc;
            atomicAdd(n_pos, rc);
        }
    }
}

// ---------------- gather + L2-normalize + bf16-cast (1 wave / row); zero-fill tail ----------------
__global__ __launch_bounds__(256) void k_gather(const float* __restrict__ emb,
                                                const int* __restrict__ P_count,
                                                const int* __restrict__ idx_c,
                                                ushort* __restrict__ Epb) {
    int w = threadIdx.x >> 6, lane = threadIdx.x & 63;
    int p = blockIdx.x * 4 + w;
    int P = *P_count;
    ushort4 o = make_ushort4(0, 0, 0, 0);
    if (p < P) {
        int row = idx_c[p];
        float4 v = *(const float4*)&emb[(size_t)row * DIM + lane * 4];
        float ss = v.x * v.x + v.y * v.y + v.z * v.z + v.w * v.w;
        #pragma unroll
        for (int off = 32; off; off >>= 1) ss += __shfl_xor(ss, off, 64);
        float inv = 1.0f / fmaxf(sqrtf(ss), 1e-12f);
        o.x = f2bf(v.x * inv); o.y = f2bf(v.y * inv);
        o.z = f2bf(v.z * inv); o.w = f2bf(v.w * inv);
    }
    *(ushort4*)&Epb[(size_t)p * DIM + lane * 4] = o;   // rows >= P are zeroed
}

// ---------------- main: MFMA S-tiles + fixed-max (M=0) exp-sum + pos-sum ----------------
// Block: 256 thr / 4 waves; tile 64x64. Wave w: rows (w&1)*32..+32, cols (w>>1)*32..+32.
// LDS staged in fragment order: 16B unit u = (G*64 + sub*16 + rl), G = rg8*8+ks,
// holding Epb[base + rg8*16 + rl][ks*32 + sub*8 .. +8]  -> ds_read_b128 lane-contiguous.
__global__ __launch_bounds__(256) void k_main(
    const ushort* __restrict__ Epb, const int* __restrict__ P_count,
    const int* __restrict__ meta, float* __restrict__ s_glob, float* __restrict__ pos_glob) {
    __shared__ ushort sm[64 * 256];   // 32 KB, reused for A then per-ct B tiles
    int P = *P_count;
    int rt = blockIdx.x;
    int ntiles = (P + 63) >> 6;
    if (rt >= ntiles) return;
    int slice = blockIdx.y;
    int t = threadIdx.x;
    int w = t >> 6, l = t & 63;
    int rowbase = rt * 64;

    // ---- stage A tile (rows rowbase..+63)
    #pragma unroll
    for (int it = 0; it < 8; ++it) {
        int u = it * 256 + t;
        int G = u >> 6, l6 = u & 63;
        int rl = l6 & 15, sub = l6 >> 4;
        int r = rowbase + (G >> 3) * 16 + rl;
        int k0 = (G & 7) * 32 + sub * 8;
        uint4 v = *(const uint4*)&Epb[(size_t)r * DIM + k0];
        *(uint4*)&sm[u * 8] = v;
    }
    __syncthreads();
    // ---- hoist A fragments to registers (2 rowgroups x 8 K-steps)
    short8 af[2][8];
    #pragma unroll
    for (int rg = 0; rg < 2; ++rg) {
        int rgi = (w & 1) * 2 + rg;
        #pragma unroll
        for (int ks = 0; ks < 8; ++ks)
            af[rg][ks] = *(const short8*)&sm[((rgi * 8 + ks) * 64 + l) * 8];
    }
    // ---- row metadata (8 rows per lane; garbage beyond P is never consumed)
    int mp[8];
    #pragma unroll
    for (int rg = 0; rg < 2; ++rg)
        #pragma unroll
        for (int j = 0; j < 4; ++j)
            mp[rg * 4 + j] = meta[rowbase + (w & 1) * 32 + rg * 16 + (l >> 4) * 4 + j];

    float s_acc[8] = {0.f, 0.f, 0.f, 0.f, 0.f, 0.f, 0.f, 0.f};
    float p_acc[8] = {0.f, 0.f, 0.f, 0.f, 0.f, 0.f, 0.f, 0.f};
    int cgi0 = (w >> 1) * 2, cgi1 = cgi0 + 1;
    __syncthreads();  // all waves done with A in LDS

    for (int ct = slice; ct < ntiles; ct += NSLICE) {
        int colbase = ct * 64;
        // ---- stage B tile (rows colbase..+63 of Epb)
        #pragma unroll
        for (int it = 0; it < 8; ++it) {
            int u = it * 256 + t;
            int G = u >> 6, l6 = u & 63;
            int rl = l6 & 15, sub = l6 >> 4;
            int r = colbase + (G >> 3) * 16 + rl;
            int k0 = (G & 7) * 32 + sub * 8;
            uint4 v = *(const uint4*)&Epb[(size_t)r * DIM + k0];
            *(uint4*)&sm[u * 8] = v;
        }
        __syncthreads();
        f32x4 acc00 = {0.f, 0.f, 0.f, 0.f}, acc01 = {0.f, 0.f, 0.f, 0.f};
        f32x4 acc10 = {0.f, 0.f, 0.f, 0.f}, acc11 = {0.f, 0.f, 0.f, 0.f};
        #pragma unroll
        for (int ks = 0; ks < 8; ++ks) {
            short8 b0 = *(const short8*)&sm[((cgi0 * 8 + ks) * 64 + l) * 8];
            short8 b1 = *(const short8*)&sm[((cgi1 * 8 + ks) * 64 + l) * 8];
            acc00 = __builtin_amdgcn_mfma_f32_16x16x32_bf16(af[0][ks], b0, acc00, 0, 0, 0);
            acc01 = __builtin_amdgcn_mfma_f32_16x16x32_bf16(af[0][ks], b1, acc01, 0, 0, 0);
            acc10 = __builtin_amdgcn_mfma_f32_16x16x32_bf16(af[1][ks], b0, acc10, 0, 0, 0);
            acc11 = __builtin_amdgcn_mfma_f32_16x16x32_bf16(af[1][ks], b1, acc11, 0, 0, 0);
        }
        // ---- epilogue: C/D layout col=lane&15, row=(lane>>4)*4+reg (m89-verified)
        #pragma unroll
        for (int cg = 0; cg < 2; ++cg) {
            int q = colbase + (cgi0 + cg) * 16 + (l & 15);
            bool vq = q < P;
            int mq = meta[q];
            #pragma unroll
            for (int rg = 0; rg < 2; ++rg) {
                f32x4 a = (rg == 0) ? (cg == 0 ? acc00 : acc01)
                                    : (cg == 0 ? acc10 : acc11);
                #pragma unroll
                for (int j = 0; j < 4; ++j) {
                    float sv = a[j];
                    int mpv = mp[rg * 4 + j];
                    bool val = vq && (((mq ^ mpv) & 15) != 0);   // valid <=> diff graph
                    float e = __expf(sv * INV_T);                // fixed max = 0 (|logit|<=10)
                    s_acc[rg * 4 + j] += val ? e : 0.f;
                    p_acc[rg * 4 + j] += (val && ((mq >> 4) == (mpv >> 4))) ? sv : 0.f;
                }
            }
        }
        __syncthreads();  // before next B overwrite
    }

    // ---- reduce over the 16 lanes sharing each row (cols), then atomics
    #pragma unroll
    for (int off = 1; off < 16; off <<= 1)
        #pragma unroll
        for (int i = 0; i < 8; ++i) {
            s_acc[i] += __shfl_xor(s_acc[i], off, 64);
            p_acc[i] += __shfl_xor(p_acc[i], off, 64);
        }
    if ((l & 15) == 0) {
        #pragma unroll
        for (int rg = 0; rg < 2; ++rg)
            #pragma unroll
            for (int j = 0; j < 4; ++j) {
                int p = rowbase + (w & 1) * 32 + rg * 16 + (l >> 4) * 4 + j;
                if (p < P) {
                    atomicAdd(&s_glob[p], s_acc[rg * 4 + j]);
                    atomicAdd(&pos_glob[p], p_acc[rg * 4 + j]);
                }
            }
    }
}

// ---------------- final reduce ----------------
__global__ __launch_bounds__(256) void k_reduce(
    const int* __restrict__ P_count, const int* __restrict__ n_pos_p,
    const int* __restrict__ rc_c, const float* __restrict__ s_glob,
    const float* __restrict__ pos_glob, float* __restrict__ out) {
    __shared__ float red[256];
    __shared__ float red2[256];
    int P = *P_count;
    float nce_local = 0.f, pos_local = 0.f;
    for (int p = threadIdx.x; p < P; p += 256) {
        float lse = logf(s_glob[p]);   // fixed max = 0
        nce_local += (float)rc_c[p] * lse;
        pos_local += pos_glob[p];
    }
    red[threadIdx.x] = nce_local;
    red2[threadIdx.x] = pos_local;
    __syncthreads();
    for (int wd = 128; wd; wd >>= 1) {
        if (threadIdx.x < (unsigned)wd) {
            red[threadIdx.x] += red[threadIdx.x + wd];
            red2[threadIdx.x] += red2[threadIdx.x + wd];
        }
        __syncthreads();
    }
    if (threadIdx.x == 0) {
        int npos = *n_pos_p;
        float result = 0.f;
        if (npos > 0) {
            float possum = red2[0];
            float n_pairs = (float)(npos / 2);
            float pos_loss = (n_pairs - 0.5f * possum) / n_pairs;
            float nce = (red[0] - possum * INV_T) / (float)npos;
            result = pos_loss + nce;
        }
        out[0] = result;
    }
}

extern "C" void kernel_launch(void* const* d_in, const int* in_sizes, int n_in,
                              void* d_out, int out_size, void* d_ws, size_t ws_size,
                              hipStream_t stream) {
    const float* emb  = (const float*)d_in[0];
    const int* labels = (const int*)d_in[1];
    const int* graphs = (const int*)d_in[2];
    const int* cats   = (const int*)d_in[3];

    char* ws = (char*)d_ws;
    size_t off = 0;
    ushort* Epb = (ushort*)(ws + off); off += (size_t)N_NODES * DIM * 2;   // 4 MB
    int* cnt     = (int*)(ws + off); off += NLAB * NGRAPH * 4;             // 128 KB (zeroed)
    int* tot     = (int*)(ws + off); off += NLAB * 4;                      // 8 KB   (zeroed)
    int* P_count = (int*)(ws + off); off += 4;                             // (zeroed)
    int* n_pos   = (int*)(ws + off); off += 4;                             // (zeroed)
    size_t zero1 = (size_t)NLAB * NGRAPH * 4 + NLAB * 4 + 8;
    off = (off + 255) & ~(size_t)255;
    int* idx_c = (int*)(ws + off); off += N_NODES * 4;
    int* rc_c  = (int*)(ws + off); off += N_NODES * 4;
    int* meta  = (int*)(ws + off); off += N_NODES * 4;
    float* s_glob   = (float*)(ws + off); off += N_NODES * 4;              // (zeroed)
    float* pos_glob = (float*)(ws + off); off += N_NODES * 4;              // (zeroed)

    hipMemsetAsync(cnt, 0, zero1, stream);
    hipMemsetAsync(s_glob, 0, (size_t)N_NODES * 8, stream);
    k_counts<<<N_NODES / 256, 256, 0, stream>>>(labels, graphs, cats, cnt, tot);
    k_compact<<<N_NODES / 256, 256, 0, stream>>>(labels, graphs, cats, cnt, tot,
                                                 P_count, n_pos, idx_c, meta, rc_c);
    k_gather<<<N_NODES / 4, 256, 0, stream>>>(emb, P_count, idx_c, Epb);
    dim3 grid(N_NODES / 64, NSLICE);
    k_main<<<grid, 256, 0, stream>>>(Epb, P_count, meta, s_glob, pos_glob);
    k_reduce<<<1, 256, 0, stream>>>(P_count, n_pos, rc_c, s_glob, pos_glob, (float*)d_out);
}